// Round 13
// baseline (136.843 us; speedup 1.0000x reference)
//
#include <hip/hip_runtime.h>
#include <hip/hip_bf16.h>

using f32x4  = __attribute__((ext_vector_type(4))) float;
using bf16x8 = __attribute__((ext_vector_type(8))) short;
using s16x4  = __attribute__((ext_vector_type(4))) short;

constexpr int kB  = 8;
constexpr int kA  = 32;
constexpr int kT  = 64;
constexpr int kNH = 256;
constexpr int kNE = 256;                 // NEMB
constexpr int kE  = kA * (kA - 1);       // 992
constexpr int kM  = kB * kA * kT;        // 16384 rows of h
constexpr int kK  = kNH;                 // 256
constexpr int kN  = 2 * kNE;             // 512 (Ps | Pr)

__device__ __forceinline__ unsigned short rne_bf16(float f) {
    unsigned int u = __float_as_uint(f);
    u += 0x7fffu + ((u >> 16) & 1u);
    return (unsigned short)(u >> 16);
}
__device__ __forceinline__ float bf16_f32(unsigned short h) {
    return __uint_as_float(((unsigned int)h) << 16);
}
// 2-way split: x ~= hi + mid (each bf16), residual <= 2^-17 |x|
__device__ __forceinline__ void split2(float x, unsigned short& h, unsigned short& m) {
    h = rne_bf16(x);
    float r1 = x - bf16_f32(h);
    m = rne_bf16(r1);
}

#define GLL(g, l) __builtin_amdgcn_global_load_lds( \
    (const __attribute__((address_space(1))) void*)(g), \
    (__attribute__((address_space(3))) void*)(l), 16, 0, 0)

// flags: 64B-strided slots. aflag[bm]=slot bm, pflag[bm]=slot 128+bm,
// fw[xcd]=slot 256+xcd, fl[xcd]=slot 264+xcd. RELAXED atomics only (R10:
// acquire-polling emitted buffer_inv per poll -> L2 thrash -> 318us).
// All bulk flows are same-XCD (L2 = coherence point; consumer CUs never
// cached those lines; vector L1 is write-through). Producers drain stores
// via __syncthreads()'s implicit vmcnt(0) BEFORE tid0 bumps the flag.
#define FLAG_ADD(slot) __hip_atomic_fetch_add(&flags[(slot) * 16], 1u, \
    __ATOMIC_RELAXED, __HIP_MEMORY_SCOPE_AGENT)
#define FLAG_WAIT(slot, tgt)                                                   \
    while (__hip_atomic_load(&flags[(slot) * 16], __ATOMIC_RELAXED,            \
                             __HIP_MEMORY_SCOPE_AGENT) < (unsigned)(tgt))      \
        __builtin_amdgcn_s_sleep(1)

// ============================================================================
// Single fused kernel, producer/consumer role split (GEMM overlaps the
// write-bound gather). R12 bug: gather role used j=idx (32..63) instead of
// j=idx-32 -> gi out of range -> LUT reads ran into the NEXT XCD's copy ->
// stores landed on wrong edges (absmax 3.19). Fixed here; roles otherwise
// identical.
//   bids 0..255  : GEMM blocks  — 2 tiles each (shared bm), bump pflag/tile.
//   bids 256..511: gather blocks — 2 adjacent (gi,gj) units (shared gi:
//                  ps[4] loaded once, pr[8]), nontemporal stores.
// Split phase runs on ALL 512 blocks. All co-resident (32KB LDS,
// launch_bounds(256,2)) -> spins always progress. DAG: S -> G -> R.
// XCD x owns batch x end-to-end.
// ============================================================================
__global__ __launch_bounds__(256, 2) void k_all(const float* __restrict__ hsrc,
                                                const float* __restrict__ W,
                                                const float* __restrict__ rel_rec,
                                                const float* __restrict__ rel_send,
                                                const float* __restrict__ bias,
                                                unsigned short* __restrict__ a1,
                                                unsigned short* __restrict__ a2,
                                                unsigned short* __restrict__ b1,
                                                unsigned short* __restrict__ b2,
                                                float* __restrict__ P,
                                                int* __restrict__ ij2e,
                                                unsigned int* flags,
                                                float* __restrict__ out) {
    __shared__ unsigned short sAh[128 * 32], sAm[128 * 32];   // 8 KB each
    __shared__ unsigned short sBh[128 * 32], sBm[128 * 32];   // total 32768 B

    const int bid = blockIdx.x;              // 0..511
    const int tid = threadIdx.x;
    const int xcd = bid & 7;
    const int idx = bid >> 3;                // 0..63

    // per-XCD copies of the B (W-split) panels and edge LUT
    unsigned short* b1x = b1 + (size_t)xcd * (kN * kK);
    unsigned short* b2x = b2 + (size_t)xcd * (kN * kK);
    int*            lut = ij2e + xcd * 1024;

    // -------------------- phase S: split (all 512 blocks) --------------------
    {
        const int sbn = idx & 3;
        const int sbm = xcd * 16 + (idx >> 2);
        const int row0 = sbm * 128 + sbn * 32;
        const size_t base4 = (size_t)row0 * 64;         // f32x4 units (256 f32/row)
#pragma unroll
        for (int r = 0; r < 8; ++r) {
            size_t i4 = base4 + (size_t)r * 256 + tid;
            f32x4 v = ((const f32x4*)hsrc)[i4];
            s16x4 o1, o2;
#pragma unroll
            for (int j = 0; j < 4; ++j) {
                unsigned short h, m;
                split2(v[j], h, m);
                o1[j] = (short)h; o2[j] = (short)m;
            }
            *(s16x4*)(a1 + i4 * 4) = o1;
            *(s16x4*)(a2 + i4 * 4) = o2;
        }
        // W-split into THIS XCD's copy: block idx handles B^T rows idx*8..+7
#pragma unroll
        for (int r = 0; r < 8; ++r) {
            int n = idx * 8 + r;             // 0..511
            float wv = (n < kNE) ? W[(size_t)n * (2 * kNH) + tid]
                                 : W[(size_t)(n - kNE) * (2 * kNH) + kNH + tid];
            unsigned short wh, wm;
            split2(wv, wh, wm);
            b1x[(size_t)n * kK + tid] = wh;
            b2x[(size_t)n * kK + tid] = wm;
        }
        // edge LUT into THIS XCD's copy: blocks idx 0..3
        if (idx < 4) {
            int e = idx * 256 + tid;
            if (e < kE) {
                int ir = 0, is = 0;
                for (int a = 0; a < kA; ++a) {
                    if (rel_rec[(size_t)e * kA + a]  > 0.5f) ir = a;
                    if (rel_send[(size_t)e * kA + a] > 0.5f) is = a;
                }
                lut[is * kA + ir] = e;
            }
        }
        __syncthreads();                     // drains all waves' stores (vmcnt)
        if (tid == 0) {
            FLAG_ADD(sbm);                   // aflag
            FLAG_ADD(256 + xcd);             // fw (target 64)
            if (idx < 4) FLAG_ADD(264 + xcd);// fl (target 4)
        }
    }

    if (bid < 256) {
        // -------------------- role G: GEMM, 2 tiles sharing bm ---------------
        const int j  = idx;                  // 0..31
        const int bm = xcd * 16 + (j >> 1);
        const int bn0 = (j & 1) * 2;         // tiles (bm, bn0) and (bm, bn0+1)

        if (tid == 0) { FLAG_WAIT(bm, 4); FLAG_WAIT(256 + xcd, 64); }
        __syncthreads();
        asm volatile("" ::: "memory");

        const int lane = tid & 63;
        const int wave = tid >> 6;
        const int wr = wave >> 1, wc = wave & 1;

        const int sr   = tid >> 2;                      // row within 64-row half-tile
        const int scb  = (tid & 3) << 4;                // byte col within 64B row
        const int scbs = scb ^ (((sr >> 1) & 3) << 4);  // pre-swizzled source col
        const size_t rA  = (size_t)(bm * 128 + sr) * kK + (scbs >> 1);
        const size_t rA1 = rA + (size_t)64 * kK;
        const int l0 = tid * 8, l1 = 64 * 32 + tid * 8;

        const int fr  = lane & 15;
        const int fkb = (lane >> 4) << 4;
        const int swz = ((fr >> 1) & 3) << 4;
        const int col = lane & 15;
        const int rb  = (lane >> 4) << 2;

        for (int tn = 0; tn < 2; ++tn) {
            const int bn = bn0 + tn;
            const size_t rB  = (size_t)(bn * 128 + sr) * kK + (scbs >> 1);
            const size_t rB1 = rB + (size_t)64 * kK;

            f32x4 acc[4][4] = {};
#pragma unroll
            for (int kt = 0; kt < 8; ++kt) {
                const int kk = kt * 32;
                __syncthreads();             // previous compute done
                GLL(a1  + rA + kk, sAh + l0);  GLL(a1  + rA1 + kk, sAh + l1);
                GLL(a2  + rA + kk, sAm + l0);  GLL(a2  + rA1 + kk, sAm + l1);
                GLL(b1x + rB + kk, sBh + l0);  GLL(b1x + rB1 + kk, sBh + l1);
                GLL(b2x + rB + kk, sBm + l0);  GLL(b2x + rB1 + kk, sBm + l1);
                __syncthreads();             // drain staging

                bf16x8 ah[4], am[4], bh[4], bmf[4];
#pragma unroll
                for (int mi = 0; mi < 4; ++mi) {
                    int row = wr * 64 + mi * 16 + fr;
                    int off = row * 64 + (fkb ^ swz);
                    ah[mi] = *(const bf16x8*)((const char*)sAh + off);
                    am[mi] = *(const bf16x8*)((const char*)sAm + off);
                }
#pragma unroll
                for (int ni = 0; ni < 4; ++ni) {
                    int row = wc * 64 + ni * 16 + fr;
                    int off = row * 64 + (fkb ^ swz);
                    bh[ni]  = *(const bf16x8*)((const char*)sBh + off);
                    bmf[ni] = *(const bf16x8*)((const char*)sBm + off);
                }
#pragma unroll
                for (int mi = 0; mi < 4; ++mi)
#pragma unroll
                    for (int ni = 0; ni < 4; ++ni) {
                        f32x4 c = acc[mi][ni];
                        c = __builtin_amdgcn_mfma_f32_16x16x32_bf16(ah[mi], bh[ni],  c, 0, 0, 0);
                        c = __builtin_amdgcn_mfma_f32_16x16x32_bf16(ah[mi], bmf[ni], c, 0, 0, 0);
                        c = __builtin_amdgcn_mfma_f32_16x16x32_bf16(am[mi], bh[ni],  c, 0, 0, 0);
                        acc[mi][ni] = c;
                    }
            }

            // epilogue: C/D layout col=lane&15, row=(lane>>4)*4+r [m89-verified]
#pragma unroll
            for (int mi = 0; mi < 4; ++mi)
#pragma unroll
                for (int ni = 0; ni < 4; ++ni) {
                    int n = bn * 128 + wc * 64 + ni * 16 + col;
#pragma unroll
                    for (int r = 0; r < 4; ++r) {
                        int m = bm * 128 + wr * 64 + mi * 16 + rb + r;
                        P[(size_t)m * kN + n] = acc[mi][ni][r];
                    }
                }
            __syncthreads();                 // drains P stores (vmcnt)
            if (tid == 0) FLAG_ADD(128 + bm);// pflag: 2 blocks x 2 tiles -> 4
        }
    } else {
        // -------------------- role R: gather, 2 units sharing gi -------------
        const int j   = idx - 32;            // 0..31  (R12 BUG: was idx)
        const int b   = xcd;
        const int gi  = j >> 2;              // 0..7
        const int gj0 = (2 * j) & 7;         // units (gi,gj0) and (gi,gj0+1)
        const int ms = b * 16 + 2 * gi;      // sender tiles
        const int mr = b * 16 + 2 * gj0;     // receiver tiles (4 consecutive)
        if (tid == 0) {
            FLAG_WAIT(264 + xcd, 4);         // LUT ready
            FLAG_WAIT(128 + ms, 4);      FLAG_WAIT(128 + ms + 1, 4);
            FLAG_WAIT(128 + mr, 4);      FLAG_WAIT(128 + mr + 1, 4);
            FLAG_WAIT(128 + mr + 2, 4);  FLAG_WAIT(128 + mr + 3, 4);
        }
        __syncthreads();
        asm volatile("" ::: "memory");

        int* se = (int*)sAh;                 // alias GEMM LDS
        if (tid < 32) {
            int si = tid >> 3, rj = tid & 7; // 4 senders x 8 receivers
            int i = gi * 4 + si, jj = gj0 * 4 + rj;
            se[tid] = (i == jj) ? -1 : lut[i * kA + jj];
        }
        __syncthreads();
        int e[32];
#pragma unroll
        for (int k = 0; k < 32; ++k) e[k] = se[k];

        const int c = tid & 63;              // f32x4 col 0..63
        const int w = tid >> 6;
        f32x4 bv = ((const f32x4*)bias)[c];
        const float* Pb = P + (size_t)(b * kA) * kT * kN;
        float* outb = out + (size_t)b * kE * kT * kNE;

        for (int i = 0; i < 16; ++i) {
            int t = w + i * 4;
            f32x4 ps[4], pr[8];
#pragma unroll
            for (int si = 0; si < 4; ++si)
                ps[si] = *(const f32x4*)(Pb + ((size_t)(gi * 4 + si) * kT + t) * kN + c * 4);
#pragma unroll
            for (int rj = 0; rj < 8; ++rj)
                pr[rj] = *(const f32x4*)(Pb + ((size_t)(gj0 * 4 + rj) * kT + t) * kN + kNE + c * 4);
#pragma unroll
            for (int si = 0; si < 4; ++si)
#pragma unroll
                for (int rj = 0; rj < 8; ++rj) {
                    int ee = e[si * 8 + rj];
                    if (ee >= 0) {
                        f32x4 v = ps[si] + pr[rj] + bv;
                        __builtin_nontemporal_store(
                            v, (f32x4*)(outb + ((size_t)ee * kT + t) * kNE + c * 4));
                    }
                }
        }
    }
}

extern "C" void kernel_launch(void* const* d_in, const int* in_sizes, int n_in,
                              void* d_out, int out_size, void* d_ws, size_t ws_size,
                              hipStream_t stream) {
    const float* h    = (const float*)d_in[0];
    const float* rrec = (const float*)d_in[1];
    const float* rsnd = (const float*)d_in[2];
    const float* W    = (const float*)d_in[3];
    const float* bias = (const float*)d_in[4];
    float* out = (float*)d_out;

    char* ws = (char*)d_ws;
    const size_t MB = 1024 * 1024;
    unsigned short* Ah = (unsigned short*)(ws);                  // 8 MB
    unsigned short* Am = (unsigned short*)(ws + 8 * MB);         // 8 MB
    unsigned short* Bh = (unsigned short*)(ws + 16 * MB);        // 8 x 256 KB = 2 MB
    unsigned short* Bm = (unsigned short*)(ws + 18 * MB);        // 2 MB
    float* P   = (float*)(ws + 20 * MB);                         // 32 MB
    int* ij2e  = (int*)(ws + 52 * MB);                           // 8 x 4 KB
    unsigned int* flags = (unsigned int*)(ws + 52 * MB + 64 * 1024);  // ~17.4 KB

    hipMemsetAsync(flags, 0, 32 * 1024, stream);
    k_all<<<dim3(512), dim3(256), 0, stream>>>(h, W, rrec, rsnd, bias,
                                               Ah, Am, Bh, Bm, P, ij2e, flags, out);
}

// Round 14
// 129.988 us; speedup vs baseline: 1.0527x; 1.0527x over previous
//
#include <hip/hip_runtime.h>
#include <hip/hip_bf16.h>

using f32x4  = __attribute__((ext_vector_type(4))) float;
using bf16x8 = __attribute__((ext_vector_type(8))) short;
using s16x4  = __attribute__((ext_vector_type(4))) short;

constexpr int kB  = 8;
constexpr int kA  = 32;
constexpr int kT  = 64;
constexpr int kNH = 256;
constexpr int kNE = 256;                 // NEMB
constexpr int kE  = kA * (kA - 1);       // 992
constexpr int kM  = kB * kA * kT;        // 16384 rows of h
constexpr int kK  = kNH;                 // 256
constexpr int kN  = 2 * kNE;             // 512 (Ps | Pr)

__device__ __forceinline__ unsigned short rne_bf16(float f) {
    unsigned int u = __float_as_uint(f);
    u += 0x7fffu + ((u >> 16) & 1u);
    return (unsigned short)(u >> 16);
}
__device__ __forceinline__ float bf16_f32(unsigned short h) {
    return __uint_as_float(((unsigned int)h) << 16);
}
// 2-way split: x ~= hi + mid (each bf16), residual <= 2^-17 |x|
__device__ __forceinline__ void split2(float x, unsigned short& h, unsigned short& m) {
    h = rne_bf16(x);
    float r1 = x - bf16_f32(h);
    m = rne_bf16(r1);
}

// ---- fused split: h -> Ah/Am ; W -> Bh/Bm (B^T form) ; edge LUT ----------
__global__ __launch_bounds__(256) void k_split_all(const float* __restrict__ hsrc,
                                                   unsigned short* __restrict__ a1,
                                                   unsigned short* __restrict__ a2,
                                                   const float* __restrict__ W,
                                                   unsigned short* __restrict__ b1,
                                                   unsigned short* __restrict__ b2,
                                                   const float* __restrict__ rel_rec,
                                                   const float* __restrict__ rel_send,
                                                   int* __restrict__ ij2e) {
    const int bidx = blockIdx.x;
    if (bidx < 4096) {                                  // h: 16384*256 elems / 4
        int idx = bidx * 256 + threadIdx.x;
        f32x4 v = ((const f32x4*)hsrc)[idx];
        s16x4 o1, o2;
#pragma unroll
        for (int j = 0; j < 4; ++j) {
            unsigned short h, m;
            split2(v[j], h, m);
            o1[j] = (short)h; o2[j] = (short)m;
        }
        *(s16x4*)(a1 + (size_t)idx * 4) = o1;
        *(s16x4*)(a2 + (size_t)idx * 4) = o2;
        return;
    }
    const int wb  = bidx - 4096;                        // 0..127
    int idx = wb * 256 + threadIdx.x;                   // per 4 elems; 32768 total
    int n  = idx >> 6;                                  // 0..511
    int k4 = (idx & 63) << 2;                           // 0..252
    const float* s = (n < kNE) ? (W + (size_t)n * (2 * kNH) + k4)
                               : (W + (size_t)(n - kNE) * (2 * kNH) + kNH + k4);
    f32x4 v = *(const f32x4*)s;
    s16x4 o1, o2;
#pragma unroll
    for (int j = 0; j < 4; ++j) {
        unsigned short h, m;
        split2(v[j], h, m);
        o1[j] = (short)h; o2[j] = (short)m;
    }
    size_t off = (size_t)n * kK + k4;
    *(s16x4*)(b1 + off) = o1;
    *(s16x4*)(b2 + off) = o2;

    // inverse edge LUT: ij2e[send*32 + recv] = e  (first 4 W-blocks)
    if (wb < 4) {
        int e = wb * 256 + threadIdx.x;
        if (e < kE) {
            int ir = 0, is = 0;
            for (int a = 0; a < kA; ++a) {
                if (rel_rec[(size_t)e * kA + a]  > 0.5f) ir = a;
                if (rel_send[(size_t)e * kA + a] > 0.5f) is = a;
            }
            ij2e[is * kA + ir] = e;
        }
    }
}

// ---- GEMM: P[16384][512] = A[16384][256] * Bcat[512][256]^T, split-f32 ---
// 128x128 tile, BK=32, dbuf LDS, 3 MFMA terms (ah*bh + ah*bm + am*bh).
// COUNTED-vmcnt pipeline (T3+T4, m218): per k-tile
//   STAGE(next) ; s_waitcnt vmcnt(8)  <- waits only the PREVIOUS tile's 8
//   raw s_barrier ; ds_read+MFMA ; raw s_barrier (no waitcnt drain)
// so the 8 just-issued global_load_lds stay in flight across both barriers
// and the whole compute phase. R7 used __syncthreads() = vmcnt(0) drain per
// tile — the documented ~20% structural stall; this is the counted fix.
// Race audit: barrier#2 of iter k orders all waves' reads of buf[cur]
// before iter k+1 restages it; vmcnt(8)+barrier#1 orders stage completion
// before reads (vmcnt accounting is in-order).
#define GLL(g, l) __builtin_amdgcn_global_load_lds( \
    (const __attribute__((address_space(1))) void*)(g), \
    (__attribute__((address_space(3))) void*)(l), 16, 0, 0)

__global__ __launch_bounds__(256, 2) void k_gemm6(const unsigned short* __restrict__ Ah,
                                                  const unsigned short* __restrict__ Am,
                                                  const unsigned short* __restrict__ Bh,
                                                  const unsigned short* __restrict__ Bm,
                                                  float* __restrict__ P) {
    __shared__ unsigned short sAh[2][128 * 32], sAm[2][128 * 32];
    __shared__ unsigned short sBh[2][128 * 32], sBm[2][128 * 32];
    const int tid  = threadIdx.x;
    const int lane = tid & 63;
    const int wave = tid >> 6;
    const int wr = wave >> 1, wc = wave & 1;
    const int bid = blockIdx.x;                     // 0..511
    const int xcd = bid & 7;
    const int idx = bid >> 3;                       // 0..63
    const int bn  = idx & 3;                        // fastest within XCD
    const int bm  = xcd * 16 + (idx >> 2);          // batch b = xcd

    const int sr   = tid >> 2;                      // row within 64-row half-tile
    const int scb  = (tid & 3) << 4;                // byte col within 64B row
    const int scbs = scb ^ (((sr >> 1) & 3) << 4);  // pre-swizzled source col
    const size_t rA  = (size_t)(bm * 128 + sr) * kK + (scbs >> 1);
    const size_t rB  = (size_t)(bn * 128 + sr) * kK + (scbs >> 1);
    const size_t rA1 = rA + (size_t)64 * kK;
    const size_t rB1 = rB + (size_t)64 * kK;
    const int l0 = tid * 8, l1 = 64 * 32 + tid * 8;

    const int fr  = lane & 15;
    const int fkb = (lane >> 4) << 4;
    const int swz = ((fr >> 1) & 3) << 4;

    f32x4 acc[4][4] = {};

#define STAGE(buf, kk)                                                        \
    do {                                                                      \
        GLL(Ah + rA + (kk), sAh[buf] + l0);  GLL(Ah + rA1 + (kk), sAh[buf] + l1); \
        GLL(Am + rA + (kk), sAm[buf] + l0);  GLL(Am + rA1 + (kk), sAm[buf] + l1); \
        GLL(Bh + rB + (kk), sBh[buf] + l0);  GLL(Bh + rB1 + (kk), sBh[buf] + l1); \
        GLL(Bm + rB + (kk), sBm[buf] + l0);  GLL(Bm + rB1 + (kk), sBm[buf] + l1); \
    } while (0)

    STAGE(0, 0);                             // prologue: 8 loads in flight

#pragma unroll
    for (int kt = 0; kt < 8; ++kt) {
        const int cur = kt & 1;
        if (kt < 7) {
            STAGE(cur ^ 1, (kt + 1) * 32);   // 8 more in flight (16 total)
            asm volatile("s_waitcnt vmcnt(8)" ::: "memory");   // prev tile landed
        } else {
            asm volatile("s_waitcnt vmcnt(0)" ::: "memory");   // final tile landed
        }
        __builtin_amdgcn_s_barrier();        // all waves' stage of cur complete

        bf16x8 ah[4], am[4], bh[4], bmf[4];
#pragma unroll
        for (int mi = 0; mi < 4; ++mi) {
            int row = wr * 64 + mi * 16 + fr;
            int off = row * 64 + (fkb ^ swz);
            ah[mi] = *(const bf16x8*)((const char*)sAh[cur] + off);
            am[mi] = *(const bf16x8*)((const char*)sAm[cur] + off);
        }
#pragma unroll
        for (int ni = 0; ni < 4; ++ni) {
            int row = wc * 64 + ni * 16 + fr;
            int off = row * 64 + (fkb ^ swz);
            bh[ni]  = *(const bf16x8*)((const char*)sBh[cur] + off);
            bmf[ni] = *(const bf16x8*)((const char*)sBm[cur] + off);
        }
#pragma unroll
        for (int mi = 0; mi < 4; ++mi)
#pragma unroll
            for (int ni = 0; ni < 4; ++ni) {
                f32x4 c = acc[mi][ni];
                c = __builtin_amdgcn_mfma_f32_16x16x32_bf16(ah[mi], bh[ni],  c, 0, 0, 0);
                c = __builtin_amdgcn_mfma_f32_16x16x32_bf16(ah[mi], bmf[ni], c, 0, 0, 0);
                c = __builtin_amdgcn_mfma_f32_16x16x32_bf16(am[mi], bh[ni],  c, 0, 0, 0);
                acc[mi][ni] = c;
            }
        __builtin_amdgcn_s_barrier();        // reads of cur done before restage
    }
#undef STAGE

    // epilogue: C/D layout col=lane&15, row=(lane>>4)*4+r   [m89-verified]
    const int col = lane & 15;
    const int rb  = (lane >> 4) << 2;
#pragma unroll
    for (int mi = 0; mi < 4; ++mi)
#pragma unroll
        for (int ni = 0; ni < 4; ++ni) {
            int n = bn * 128 + wc * 64 + ni * 16 + col;
#pragma unroll
            for (int r = 0; r < 4; ++r) {
                int m = bm * 128 + wr * 64 + mi * 16 + rb + r;
                P[(size_t)m * kN + n] = acc[mi][ni][r];
            }
        }
}

// ---- gather: 4x4 atom-group blocking, t split over 2 blocks --------------
// block = (b, th, gi, gj): 16 edges, 32 t-slots. 1024 blocks = 4/CU.
// b = bid&7 pins each batch's P slice (4MB) to the XCD that produced it;
// nontemporal output stores keep P L2-resident.
__global__ __launch_bounds__(256) void k_gather2(const float* __restrict__ P,
                                                 const float* __restrict__ bias,
                                                 const int* __restrict__ ij2e,
                                                 float* __restrict__ out) {
    const int bid = blockIdx.x;              // 0..1023
    const int b  = bid & 7;
    const int th = (bid >> 3) & 1;
    const int gi = (bid >> 4) & 7;
    const int gj = bid >> 7;
    __shared__ int se[16];
    if (threadIdx.x < 16) {
        int si = threadIdx.x >> 2, rj = threadIdx.x & 3;
        int i = gi * 4 + si, j = gj * 4 + rj;
        se[threadIdx.x] = (i == j) ? -1 : ij2e[i * kA + j];
    }
    __syncthreads();
    int e[16];
#pragma unroll
    for (int k = 0; k < 16; ++k) e[k] = se[k];

    const int c  = threadIdx.x & 63;         // f32x4 col 0..63
    const int t0 = th * 32 + (threadIdx.x >> 6);
    f32x4 bv = ((const f32x4*)bias)[c];
    const float* Pb = P + (size_t)(b * kA) * kT * kN;
    float* outb = out + (size_t)b * kE * kT * kNE;

    for (int t = t0; t < th * 32 + 32; t += 4) {
        f32x4 ps[4], pr[4];
#pragma unroll
        for (int si = 0; si < 4; ++si)
            ps[si] = *(const f32x4*)(Pb + ((size_t)(gi * 4 + si) * kT + t) * kN + c * 4);
#pragma unroll
        for (int rj = 0; rj < 4; ++rj)
            pr[rj] = *(const f32x4*)(Pb + ((size_t)(gj * 4 + rj) * kT + t) * kN + kNE + c * 4);
#pragma unroll
        for (int si = 0; si < 4; ++si)
#pragma unroll
            for (int rj = 0; rj < 4; ++rj) {
                int ee = e[si * 4 + rj];
                if (ee >= 0) {
                    f32x4 v = ps[si] + pr[rj] + bv;
                    __builtin_nontemporal_store(
                        v, (f32x4*)(outb + ((size_t)ee * kT + t) * kNE + c * 4));
                }
            }
    }
}

extern "C" void kernel_launch(void* const* d_in, const int* in_sizes, int n_in,
                              void* d_out, int out_size, void* d_ws, size_t ws_size,
                              hipStream_t stream) {
    const float* h    = (const float*)d_in[0];
    const float* rrec = (const float*)d_in[1];
    const float* rsnd = (const float*)d_in[2];
    const float* W    = (const float*)d_in[3];
    const float* bias = (const float*)d_in[4];
    float* out = (float*)d_out;

    char* ws = (char*)d_ws;
    const size_t MB = 1024 * 1024;
    unsigned short* Ah = (unsigned short*)(ws);                  // 8 MB
    unsigned short* Am = (unsigned short*)(ws + 8 * MB);         // 8 MB
    unsigned short* Bh = (unsigned short*)(ws + 16 * MB);        // 256 KB
    unsigned short* Bm = (unsigned short*)(ws + 16 * MB + 256 * 1024);
    float* P   = (float*)(ws + 17 * MB);                         // 32 MB
    int* ij2e  = (int*)(ws + 49 * MB);                           // 4 KB

    k_split_all<<<dim3(4096 + 128), dim3(256), 0, stream>>>(h, Ah, Am,
                                                            W, Bh, Bm,
                                                            rrec, rsnd, ij2e);
    k_gemm6    <<<dim3(512),        dim3(256), 0, stream>>>(Ah, Am, Bh, Bm, P);
    k_gather2  <<<dim3(1024),       dim3(256), 0, stream>>>(P, bias, ij2e, out);
}

// Round 15
// 128.880 us; speedup vs baseline: 1.0618x; 1.0086x over previous
//
#include <hip/hip_runtime.h>
#include <hip/hip_bf16.h>

using f32x4  = __attribute__((ext_vector_type(4))) float;
using bf16x8 = __attribute__((ext_vector_type(8))) short;
using s16x4  = __attribute__((ext_vector_type(4))) short;

constexpr int kB  = 8;
constexpr int kA  = 32;
constexpr int kT  = 64;
constexpr int kNH = 256;
constexpr int kNE = 256;                 // NEMB
constexpr int kE  = kA * (kA - 1);       // 992
constexpr int kM  = kB * kA * kT;        // 16384 rows of h
constexpr int kK  = kNH;                 // 256
constexpr int kN  = 2 * kNE;             // 512 (Ps | Pr)

__device__ __forceinline__ unsigned short rne_bf16(float f) {
    unsigned int u = __float_as_uint(f);
    u += 0x7fffu + ((u >> 16) & 1u);
    return (unsigned short)(u >> 16);
}
__device__ __forceinline__ float bf16_f32(unsigned short h) {
    return __uint_as_float(((unsigned int)h) << 16);
}
// 2-way split: x ~= hi + mid (each bf16), residual <= 2^-17 |x|
__device__ __forceinline__ void split2(float x, unsigned short& h, unsigned short& m) {
    h = rne_bf16(x);
    float r1 = x - bf16_f32(h);
    m = rne_bf16(r1);
}

// ---- fused split: h -> Ah/Am ; W -> Bh/Bm (B^T form) ; edge LUT ----------
__global__ __launch_bounds__(256) void k_split_all(const float* __restrict__ hsrc,
                                                   unsigned short* __restrict__ a1,
                                                   unsigned short* __restrict__ a2,
                                                   const float* __restrict__ W,
                                                   unsigned short* __restrict__ b1,
                                                   unsigned short* __restrict__ b2,
                                                   const float* __restrict__ rel_rec,
                                                   const float* __restrict__ rel_send,
                                                   int* __restrict__ ij2e) {
    const int bidx = blockIdx.x;
    if (bidx < 4096) {                                  // h: 16384*256 elems / 4
        int idx = bidx * 256 + threadIdx.x;
        f32x4 v = ((const f32x4*)hsrc)[idx];
        s16x4 o1, o2;
#pragma unroll
        for (int j = 0; j < 4; ++j) {
            unsigned short h, m;
            split2(v[j], h, m);
            o1[j] = (short)h; o2[j] = (short)m;
        }
        *(s16x4*)(a1 + (size_t)idx * 4) = o1;
        *(s16x4*)(a2 + (size_t)idx * 4) = o2;
        return;
    }
    const int wb  = bidx - 4096;                        // 0..127
    int idx = wb * 256 + threadIdx.x;                   // per 4 elems; 32768 total
    int n  = idx >> 6;                                  // 0..511
    int k4 = (idx & 63) << 2;                           // 0..252
    const float* s = (n < kNE) ? (W + (size_t)n * (2 * kNH) + k4)
                               : (W + (size_t)(n - kNE) * (2 * kNH) + kNH + k4);
    f32x4 v = *(const f32x4*)s;
    s16x4 o1, o2;
#pragma unroll
    for (int j = 0; j < 4; ++j) {
        unsigned short h, m;
        split2(v[j], h, m);
        o1[j] = (short)h; o2[j] = (short)m;
    }
    size_t off = (size_t)n * kK + k4;
    *(s16x4*)(b1 + off) = o1;
    *(s16x4*)(b2 + off) = o2;

    // inverse edge LUT: ij2e[send*32 + recv] = e  (first 4 W-blocks)
    if (wb < 4) {
        int e = wb * 256 + threadIdx.x;
        if (e < kE) {
            int ir = 0, is = 0;
            for (int a = 0; a < kA; ++a) {
                if (rel_rec[(size_t)e * kA + a]  > 0.5f) ir = a;
                if (rel_send[(size_t)e * kA + a] > 0.5f) is = a;
            }
            ij2e[is * kA + ir] = e;
        }
    }
}

// ---- GEMM: P[16384][512] = A[16384][256] * Bcat[512][256]^T, split-f32 ---
// 128x128 tile, BK=32, dbuf LDS (R7 config — best measured), 3 MFMA terms:
// ah*bh + ah*bm + am*bh. Swizzle XOR ((row>>1)&3)<<4 on both sides.
// Decode: xcd=bid&7 pins batch b=xcd to its XCD; bn fastest for A reuse.
#define GLL(g, l) __builtin_amdgcn_global_load_lds( \
    (const __attribute__((address_space(1))) void*)(g), \
    (__attribute__((address_space(3))) void*)(l), 16, 0, 0)

__global__ __launch_bounds__(256) void k_gemm5(const unsigned short* __restrict__ Ah,
                                               const unsigned short* __restrict__ Am,
                                               const unsigned short* __restrict__ Bh,
                                               const unsigned short* __restrict__ Bm,
                                               float* __restrict__ P) {
    __shared__ unsigned short sAh[2][128 * 32], sAm[2][128 * 32];
    __shared__ unsigned short sBh[2][128 * 32], sBm[2][128 * 32];
    const int tid  = threadIdx.x;
    const int lane = tid & 63;
    const int wave = tid >> 6;
    const int wr = wave >> 1, wc = wave & 1;
    const int bid = blockIdx.x;                     // 0..511
    const int xcd = bid & 7;
    const int idx = bid >> 3;                       // 0..63
    const int bn  = idx & 3;                        // fastest within XCD
    const int bm  = xcd * 16 + (idx >> 2);          // batch b = xcd

    const int sr   = tid >> 2;                      // row within 64-row half-tile
    const int scb  = (tid & 3) << 4;                // byte col within 64B row
    const int scbs = scb ^ (((sr >> 1) & 3) << 4);  // pre-swizzled source col
    const size_t rA  = (size_t)(bm * 128 + sr) * kK + (scbs >> 1);
    const size_t rB  = (size_t)(bn * 128 + sr) * kK + (scbs >> 1);
    const size_t rA1 = rA + (size_t)64 * kK;
    const size_t rB1 = rB + (size_t)64 * kK;
    const int l0 = tid * 8, l1 = 64 * 32 + tid * 8;

    const int fr  = lane & 15;
    const int fkb = (lane >> 4) << 4;
    const int swz = ((fr >> 1) & 3) << 4;

    f32x4 acc[4][4] = {};

#define STAGE(buf, kk)                                                        \
    do {                                                                      \
        GLL(Ah + rA + (kk), sAh[buf] + l0);  GLL(Ah + rA1 + (kk), sAh[buf] + l1); \
        GLL(Am + rA + (kk), sAm[buf] + l0);  GLL(Am + rA1 + (kk), sAm[buf] + l1); \
        GLL(Bh + rB + (kk), sBh[buf] + l0);  GLL(Bh + rB1 + (kk), sBh[buf] + l1); \
        GLL(Bm + rB + (kk), sBm[buf] + l0);  GLL(Bm + rB1 + (kk), sBm[buf] + l1); \
    } while (0)

    STAGE(0, 0);
    __syncthreads();                         // drain prologue loads

#pragma unroll
    for (int kt = 0; kt < 8; ++kt) {
        const int cur = kt & 1;
        if (kt < 7) STAGE(cur ^ 1, (kt + 1) * 32);   // prefetch next tile

        bf16x8 ah[4], am[4], bh[4], bmf[4];
#pragma unroll
        for (int mi = 0; mi < 4; ++mi) {
            int row = wr * 64 + mi * 16 + fr;
            int off = row * 64 + (fkb ^ swz);
            ah[mi] = *(const bf16x8*)((const char*)sAh[cur] + off);
            am[mi] = *(const bf16x8*)((const char*)sAm[cur] + off);
        }
#pragma unroll
        for (int ni = 0; ni < 4; ++ni) {
            int row = wc * 64 + ni * 16 + fr;
            int off = row * 64 + (fkb ^ swz);
            bh[ni]  = *(const bf16x8*)((const char*)sBh[cur] + off);
            bmf[ni] = *(const bf16x8*)((const char*)sBm[cur] + off);
        }
#pragma unroll
        for (int mi = 0; mi < 4; ++mi)
#pragma unroll
            for (int ni = 0; ni < 4; ++ni) {
                f32x4 c = acc[mi][ni];
                c = __builtin_amdgcn_mfma_f32_16x16x32_bf16(ah[mi], bh[ni],  c, 0, 0, 0);
                c = __builtin_amdgcn_mfma_f32_16x16x32_bf16(ah[mi], bmf[ni], c, 0, 0, 0);
                c = __builtin_amdgcn_mfma_f32_16x16x32_bf16(am[mi], bh[ni],  c, 0, 0, 0);
                acc[mi][ni] = c;
            }
        __syncthreads();                     // drain prefetch + LDS handoff
    }
#undef STAGE

    // epilogue: C/D layout col=lane&15, row=(lane>>4)*4+r   [m89-verified]
    const int col = lane & 15;
    const int rb  = (lane >> 4) << 2;
#pragma unroll
    for (int mi = 0; mi < 4; ++mi)
#pragma unroll
        for (int ni = 0; ni < 4; ++ni) {
            int n = bn * 128 + wc * 64 + ni * 16 + col;
#pragma unroll
            for (int r = 0; r < 4; ++r) {
                int m = bm * 128 + wr * 64 + mi * 16 + rb + r;
                P[(size_t)m * kN + n] = acc[mi][ni][r];
            }
        }
}

// ---- gather v4: 8x8 atom-group blocking -----------------------------------
// block = (b, th, gi, gj): 8 senders x 8 receivers = up to 64 edges, 8 t-slots.
// Per t: 16 P loads feed 64 stores (read ratio 0.25 vs 0.5 for 4x4) ->
// P logical reads 260 -> 134 MB, better L2 survival under the write stream.
// 1024 blocks = 4/CU. b=bid&7 pins P[b] to the producing XCD's L2;
// nontemporal output stores. e-table in LDS (broadcast reads, uniform branch).
__global__ __launch_bounds__(256) void k_gather3(const float* __restrict__ P,
                                                 const float* __restrict__ bias,
                                                 const int* __restrict__ ij2e,
                                                 float* __restrict__ out) {
    const int bid = blockIdx.x;              // 0..1023
    const int b  = bid & 7;
    const int th = (bid >> 3) & 7;           // t-octant
    const int gi = (bid >> 6) & 3;           // sender group (8 atoms)
    const int gj = bid >> 8;                 // receiver group (8 atoms)
    __shared__ int se[64];
    if (threadIdx.x < 64) {
        int si = threadIdx.x >> 3, rj = threadIdx.x & 7;
        int i = gi * 8 + si, j = gj * 8 + rj;
        se[threadIdx.x] = (i == j) ? -1 : ij2e[i * kA + j];
    }
    __syncthreads();

    const int c = threadIdx.x & 63;          // f32x4 col 0..63
    const int w = threadIdx.x >> 6;
    f32x4 bv = ((const f32x4*)bias)[c];
    const float* Pb = P + (size_t)(b * kA) * kT * kN;
    float* outb = out + (size_t)b * kE * kT * kNE;

#pragma unroll
    for (int it = 0; it < 2; ++it) {
        int t = th * 8 + w + it * 4;
        f32x4 ps[8], pr[8];
#pragma unroll
        for (int si = 0; si < 8; ++si)
            ps[si] = *(const f32x4*)(Pb + ((size_t)(gi * 8 + si) * kT + t) * kN + c * 4);
#pragma unroll
        for (int rj = 0; rj < 8; ++rj)
            pr[rj] = *(const f32x4*)(Pb + ((size_t)(gj * 8 + rj) * kT + t) * kN + kNE + c * 4);
#pragma unroll
        for (int si = 0; si < 8; ++si)
#pragma unroll
            for (int rj = 0; rj < 8; ++rj) {
                int ee = se[si * 8 + rj];
                if (ee >= 0) {
                    f32x4 v = ps[si] + pr[rj] + bv;
                    __builtin_nontemporal_store(
                        v, (f32x4*)(outb + ((size_t)ee * kT + t) * kNE + c * 4));
                }
            }
    }
}

extern "C" void kernel_launch(void* const* d_in, const int* in_sizes, int n_in,
                              void* d_out, int out_size, void* d_ws, size_t ws_size,
                              hipStream_t stream) {
    const float* h    = (const float*)d_in[0];
    const float* rrec = (const float*)d_in[1];
    const float* rsnd = (const float*)d_in[2];
    const float* W    = (const float*)d_in[3];
    const float* bias = (const float*)d_in[4];
    float* out = (float*)d_out;

    char* ws = (char*)d_ws;
    const size_t MB = 1024 * 1024;
    unsigned short* Ah = (unsigned short*)(ws);                  // 8 MB
    unsigned short* Am = (unsigned short*)(ws + 8 * MB);         // 8 MB
    unsigned short* Bh = (unsigned short*)(ws + 16 * MB);        // 256 KB
    unsigned short* Bm = (unsigned short*)(ws + 16 * MB + 256 * 1024);
    float* P   = (float*)(ws + 17 * MB);                         // 32 MB
    int* ij2e  = (int*)(ws + 49 * MB);                           // 4 KB

    k_split_all<<<dim3(4096 + 128), dim3(256), 0, stream>>>(h, Ah, Am,
                                                            W, Bh, Bm,
                                                            rrec, rsnd, ij2e);
    k_gemm5    <<<dim3(512),        dim3(256), 0, stream>>>(Ah, Am, Bh, Bm, P);
    k_gather3  <<<dim3(1024),       dim3(256), 0, stream>>>(P, bias, ij2e, out);
}